// Round 19
// baseline (1263.358 us; speedup 1.0000x reference)
//
#include <hip/hip_runtime.h>
#include <hip/hip_bf16.h>
#include <cmath>

// Problem constants
#define NN 512   // nodes
#define BB 32    // batch
#define HH 64    // hidden
#define TT 12    // timesteps
#define KS 3     // graph supports

// Workspace layout (float units)
#define OFF_GHI   0         // bf16 [1536][512] rows k*512+i, swizzled in j (gemm_sx)
#define OFF_GPK   786432    // bf16 fragment-major G (HI ONLY): 1536 frags x 512 shorts
#define OFF_XTH   1572864   // bf16 [768][512]
#define OFF_SX    1966080   // f32  [1536][768]
#define OFF_HHI   3145728   // bf16 [2048][512] col = b*64+q, swizzled in j(=i)
#define OFF_HLO   3670016
#define OFF_RHHI  4194304
#define OFF_BAR   4718592   // claim[8] u32 + gbar[32][2] u32 (zeroed each launch)
#define OFF_WHGH  6291456   // bf16 [128][200]
#define OFF_WHGL  6304256
#define OFF_WHUH  6317056   // bf16 [64][200]
#define OFF_WHUL  6323456
#define OFF_WXG   6329856   // f32 [6][128]
#define OFF_WXU   6330624   // f32 [6][64]

typedef __attribute__((ext_vector_type(8))) short v8s;
typedef __attribute__((ext_vector_type(4))) float f32x4;
typedef __attribute__((ext_vector_type(4))) unsigned short u16x4;

__device__ __forceinline__ unsigned short f2bf(float f) {
  union { __hip_bfloat16 h; unsigned short u; } x;
  x.h = __float2bfloat16(f);
  return x.u;
}
__device__ __forceinline__ float bf2f(unsigned short u) {
  union { unsigned short u; __hip_bfloat16 h; } x;
  x.u = u;
  return __bfloat162float(x.h);
}

__device__ __forceinline__ int swz64(int j, int key) {
  return (j & ~63) | ((((j >> 3) & 7) ^ key) << 3) | (j & 7);
}

__device__ __forceinline__ void gl_lds16(const unsigned short* g, short* l) {
  __builtin_amdgcn_global_load_lds(
      (const __attribute__((address_space(1))) void*)g,
      (__attribute__((address_space(3))) void*)l, 16, 0, 0);
}

__device__ __forceinline__ float fast_tanh(float x) {
  float e = __expf(2.f * x);
  return 1.f - 2.f / (e + 1.f);
}

// ---------------- merged prologue pack kernel (r17, unchanged) ----------------
__global__ __launch_bounds__(256) void prep_all(
    const float* __restrict__ G, const float* __restrict__ x_seq,
    const float* __restrict__ init_h, const float* __restrict__ Wg,
    const float* __restrict__ Wu,
    unsigned short* __restrict__ Ghi, unsigned short* __restrict__ Gpk,
    unsigned short* __restrict__ Xh,
    unsigned short* __restrict__ Hhi, unsigned short* __restrict__ Hlo,
    unsigned short* __restrict__ Whgh, unsigned short* __restrict__ Whgl,
    unsigned short* __restrict__ Whuh, unsigned short* __restrict__ Whul,
    float* __restrict__ Wxg, float* __restrict__ Wxu) {
  int idx = blockIdx.x * 256 + threadIdx.x;
  if (idx < 786432) {
    int j = idx & 511;
    int i = (idx >> 9) & 511;
    Ghi[(size_t)(idx >> 9) * 512 + swz64(j, i & 7)] = f2bf(G[idx]);
  } else if (idx < 884736) {
    int t = idx - 786432;
    int L = t & 63;
    int frag = t >> 6;
    int m = frag % 3;
    int kf = (frag / 3) & 1;
    int j0 = (frag / 6) & 7;
    int i0w = frag / 48;
    int w = i0w & 3, i0 = i0w >> 2;
    int R = w * 48 + m * 16 + (L & 15);
    int ksec = R >> 6;
    int i = i0 * 64 + (R & 63);
    int jb = j0 * 64 + kf * 32 + (L >> 4) * 8;
    unsigned short* dst = Gpk + (size_t)frag * 512 + L * 8;
#pragma unroll
    for (int e = 0; e < 8; ++e) dst[e] = f2bf(G[((size_t)ksec * NN + i) * NN + jb + e]);
  } else if (idx < 1277952) {
    int t2 = idx - 884736;
    int j = t2 & 511;
    int col = t2 >> 9;          // t*64 + b*2 + c
    int t = col >> 6;
    int b = (col & 63) >> 1;
    int c = col & 1;
    float v = x_seq[((size_t)(b * TT + t) * NN + j) * 2 + c];
    Xh[(size_t)col * 512 + swz64(j, col & 7)] = f2bf(v);
  } else if (idx < 2326528) {
    int t2 = idx - 1277952;
    int i = t2 & 511;
    int col = t2 >> 9;
    int b = col >> 6;
    int p = col & 63;
    float h = init_h[((size_t)b * NN + i) * HH + p];
    unsigned short hi = f2bf(h);
    size_t pos = (size_t)col * 512 + swz64(i, col & 7);
    Hhi[pos] = hi;
    Hlo[pos] = f2bf(h - bf2f(hi));
  } else if (idx < 2364544) {
    int j2 = idx - 2326528;
    if (j2 < 24576) {
      int o = j2 & 127, kq = j2 >> 7;
      int k = kq >> 6, q = kq & 63;
      float v = Wg[(size_t)(k * 66 + 2 + q) * 128 + o];
      unsigned short hi = f2bf(v);
      Whgh[o * 200 + kq] = hi;
      Whgl[o * 200 + kq] = f2bf(v - bf2f(hi));
    } else if (j2 < 36864) {
      int j = j2 - 24576;
      int o = j & 63, kq = j >> 6;
      int k = kq >> 6, q = kq & 63;
      float v = Wu[(size_t)(k * 66 + 2 + q) * 64 + o];
      unsigned short hi = f2bf(v);
      Whuh[o * 200 + kq] = hi;
      Whul[o * 200 + kq] = f2bf(v - bf2f(hi));
    } else if (j2 < 37632) {
      int j = j2 - 36864;
      int o = j & 127, kc = j >> 7;
      Wxg[kc * 128 + o] = Wg[(size_t)((kc >> 1) * 66 + (kc & 1)) * 128 + o];
    } else {
      int j = j2 - 37632;
      int o = j & 63, kc = j >> 6;
      Wxu[kc * 64 + o] = Wu[(size_t)((kc >> 1) * 66 + (kc & 1)) * 64 + o];
    }
  }
}

// ---------------- Sx precompute: Ghi @ Xhi, K = 512 (r17, unchanged) ----------------
__global__ __launch_bounds__(256) void gemm_sx(const unsigned short* __restrict__ Ghi,
                                               const unsigned short* __restrict__ Xh,
                                               float* __restrict__ Sx2) {
  __shared__ __align__(16) short sA[64 * 64];
  __shared__ __align__(16) short sB[64 * 64];
  int tid = threadIdx.x;
  int L = tid & 63, w = tid >> 6;
  int wm = (w >> 1) * 32, wn = (w & 1) * 32;
  int i0 = blockIdx.y * 64;
  int c0 = blockIdx.x * 64;
  f32x4 acc[2][2];
#pragma unroll
  for (int m = 0; m < 2; ++m)
#pragma unroll
    for (int n = 0; n < 2; ++n) acc[m][n] = (f32x4)(0.f);

  for (int j0 = 0; j0 < 512; j0 += 64) {
    __syncthreads();
#pragma unroll
    for (int u = 0; u < 2; ++u) {
      int r = w * 16 + u * 8;
      gl_lds16(Ghi + (size_t)(i0 + r + (L >> 3)) * 512 + j0 + (L & 7) * 8, sA + r * 64);
      gl_lds16(Xh + (size_t)(c0 + r + (L >> 3)) * 512 + j0 + (L & 7) * 8, sB + r * 64);
    }
    __syncthreads();
#pragma unroll
    for (int kf = 0; kf < 2; ++kf) {
      int kog = kf * 4 + (L >> 4);
      v8s af[2], bf[2];
#pragma unroll
      for (int m = 0; m < 2; ++m) {
        int row = wm + m * 16 + (L & 15);
        af[m] = *(const v8s*)(sA + row * 64 + ((kog ^ (row & 7)) << 3));
      }
#pragma unroll
      for (int n = 0; n < 2; ++n) {
        int row = wn + n * 16 + (L & 15);
        bf[n] = *(const v8s*)(sB + row * 64 + ((kog ^ (row & 7)) << 3));
      }
#pragma unroll
      for (int m = 0; m < 2; ++m)
#pragma unroll
        for (int n = 0; n < 2; ++n)
          acc[m][n] = __builtin_amdgcn_mfma_f32_16x16x32_bf16(af[m], bf[n], acc[m][n], 0, 0, 0);
    }
  }
#pragma unroll
  for (int m = 0; m < 2; ++m)
#pragma unroll
    for (int r = 0; r < 4; ++r)
#pragma unroll
      for (int n = 0; n < 2; ++n)
        Sx2[(size_t)(i0 + wm + m * 16 + (L >> 4) * 4 + r) * 768 + c0 + wn + n * 16 + (L & 15)] =
            acc[m][n][r];
}

// ---------------- persistent recurrence ----------------
// Per-b-group (8 blocks, same XCD via claim) generation barrier with
// acquire/release semantics: plain cached loads/stores within phases; the
// fences do the L2 writeback / L1(+L2) invalidate only at sync points.
__device__ __forceinline__ void groupbar(unsigned int* gb) {
  __syncthreads();  // all block stores retired
  if (threadIdx.x == 0) {
    __builtin_amdgcn_fence(__ATOMIC_RELEASE, "agent");  // publish state writes
    unsigned int g = __hip_atomic_load(gb + 1, __ATOMIC_RELAXED, __HIP_MEMORY_SCOPE_AGENT);
    unsigned int old =
        __hip_atomic_fetch_add(gb, 1u, __ATOMIC_RELEASE, __HIP_MEMORY_SCOPE_AGENT);
    if (old == 7u) {
      __hip_atomic_store(gb, 0u, __ATOMIC_RELAXED, __HIP_MEMORY_SCOPE_AGENT);
      __hip_atomic_store(gb + 1, g + 1u, __ATOMIC_RELEASE, __HIP_MEMORY_SCOPE_AGENT);
    } else {
      int sp = 0;
      while (__hip_atomic_load(gb + 1, __ATOMIC_ACQUIRE, __HIP_MEMORY_SCOPE_AGENT) == g) {
        __builtin_amdgcn_s_sleep(2);
        if (++sp > (1 << 24)) break;  // bounded: fail loud, not hang
      }
    }
    __builtin_amdgcn_fence(__ATOMIC_ACQUIRE, "agent");  // invalidate stale caches
  }
  __syncthreads();  // block loads wait for thread0's acquire
}

__global__ __launch_bounds__(512, 2) void persist(
    const unsigned short* __restrict__ Gpk,
    unsigned short* __restrict__ Hhi, unsigned short* __restrict__ Hlo,
    unsigned short* __restrict__ RHhi,
    const float* __restrict__ Sx2,
    const unsigned short* __restrict__ Whgh, const unsigned short* __restrict__ Whgl,
    const float* __restrict__ Wxg, const float* __restrict__ bg,
    const unsigned short* __restrict__ Whuh, const unsigned short* __restrict__ Whul,
    const float* __restrict__ Wxu, const float* __restrict__ bu,
    float* __restrict__ out, unsigned int* __restrict__ bar) {
  __shared__ __align__(16) char smem[83456];  // >80KB => 1 block/CU (claim capacity)
  __shared__ unsigned int sSlot;
  short* sBh = (short*)smem;               // [64][512] (64 KB)
  short* sS  = (short*)smem;               // overlay after GEMM: [64][408]
  float* sSx = (float*)(smem + 65536);     // [64][6]
  float* sZ  = (float*)(smem + 67072);     // [64][64] f32 (gate -> update)

  int tid = threadIdx.x;
  int L = tid & 63, w = tid >> 6;
  int wm = w & 3, wn = w >> 2;

  // XCD-aware slot claim (locality heuristic; correctness comes from fences)
  unsigned int xcc;
  asm volatile("s_getreg_b32 %0, hwreg(HW_REG_XCC_ID)" : "=s"(xcc));
  xcc &= 7u;
  if (tid == 0) {
    unsigned int s =
        __hip_atomic_fetch_add(bar + xcc, 1u, __ATOMIC_RELAXED, __HIP_MEMORY_SCOPE_AGENT) & 31u;
    sSlot = xcc * 32u + s;
  }
  __syncthreads();
  unsigned int slot = sSlot;
  int b = (int)(slot >> 3);        // 4 b per XCD
  int i0t = (int)(slot & 7u);
  int i0 = i0t * 64;
  int bcol = b * 64;
  unsigned int* gb = bar + 8 + b * 2;
  const unsigned short* Ap = Gpk + (size_t)(i0t * 4 + wm) * 48 * 512;

  for (int t = 0; t < TT; ++t) {
#pragma unroll 1
    for (int ph = 0; ph < 2; ++ph) {
      const int GATE = (ph == 0);
      const unsigned short* Bsrc = GATE ? Hhi : RHhi;

      // ---- stage B (hi only) + (gate only) Sx slice ----
#pragma unroll
      for (int u = 0; u < 8; ++u) {
        int col = w * 8 + u;
        gl_lds16(Bsrc + (size_t)(bcol + col) * 512 + L * 8, sBh + col * 512);
      }
      if (GATE) {
        for (int e = tid; e < 384; e += 512) {
          int il = e / 6, kc = e % 6;
          sSx[e] = Sx2[(size_t)((kc >> 1) * 512 + i0 + il) * 768 + t * 64 + b * 2 + (kc & 1)];
        }
      }
      __syncthreads();  // drains gl_lds

      // ---- main GEMM: S = Ghi @ Bhi ----
      f32x4 acc[3][2];
#pragma unroll
      for (int m = 0; m < 3; ++m)
#pragma unroll
        for (int n = 0; n < 2; ++n) acc[m][n] = (f32x4)(0.f);
#pragma unroll
      for (int it = 0; it < 8; ++it) {
        v8s ah[2][3];
#pragma unroll
        for (int kf = 0; kf < 2; ++kf)
#pragma unroll
          for (int m = 0; m < 3; ++m)
            ah[kf][m] = *(const v8s*)(Ap + (size_t)((it * 2 + kf) * 3 + m) * 512 + L * 8);
#pragma unroll
        for (int kf = 0; kf < 2; ++kf) {
          int jj = it * 64 + kf * 32 + (L >> 4) * 8;
          v8s bh[2];
#pragma unroll
          for (int n = 0; n < 2; ++n) {
            int col = wn * 32 + n * 16 + (L & 15);
            int off = col * 512 + ((jj & ~63) | (((((jj >> 3) & 7) ^ (col & 7))) << 3));
            bh[n] = *(const v8s*)(sBh + off);
          }
#pragma unroll
          for (int m = 0; m < 3; ++m)
#pragma unroll
            for (int n = 0; n < 2; ++n)
              acc[m][n] =
                  __builtin_amdgcn_mfma_f32_16x16x32_bf16(ah[kf][m], bh[n], acc[m][n], 0, 0, 0);
        }
      }
      __syncthreads();  // all sBh reads done; sS overlay may overwrite

      // ---- write S to LDS as bf16 hi/lo ----
#pragma unroll
      for (int m = 0; m < 3; ++m)
#pragma unroll
        for (int n = 0; n < 2; ++n)
#pragma unroll
          for (int r = 0; r < 4; ++r) {
            int R = wm * 48 + m * 16 + (L >> 4) * 4 + r;
            int il = R & 63, kk = R >> 6;
            int pp = wn * 32 + n * 16 + (L & 15);
            float v = acc[m][n][r];
            unsigned short hi = f2bf(v);
            sS[il * 408 + kk * 64 + pp] = (short)hi;
            sS[il * 408 + 200 + kk * 64 + pp] = (short)f2bf(v - bf2f(hi));
          }
      __syncthreads();

      // ---- epilogue: 8 waves, me = row-group, oh = col-half ----
      int me = w & 3, oh = w >> 2;
      if (GATE) {
        f32x4 acc2[4];
#pragma unroll
        for (int n = 0; n < 4; ++n) acc2[n] = (f32x4)(0.f);
#pragma unroll
        for (int s = 0; s < 3; ++s) {
          const unsigned short* Wsrc = (s < 2) ? Whgh : Whgl;
          int abase = (s == 1) ? 200 : 0;
#pragma unroll
          for (int f = 0; f < 6; ++f) {
            int k0 = f * 32 + (L >> 4) * 8;
            v8s af2 = *(const v8s*)(sS + (me * 16 + (L & 15)) * 408 + abase + k0);
#pragma unroll
            for (int n = 0; n < 4; ++n) {
              v8s bf2 = *(const v8s*)(Wsrc + (size_t)(oh * 64 + n * 16 + (L & 15)) * 200 + k0);
              acc2[n] = __builtin_amdgcn_mfma_f32_16x16x32_bf16(af2, bf2, acc2[n], 0, 0, 0);
            }
          }
        }
#pragma unroll
        for (int n = 0; n < 4; ++n) {
          int o = oh * 64 + n * 16 + (L & 15);
          int il0 = me * 16 + (L >> 4) * 4;
          float sg[4];
#pragma unroll
          for (int r = 0; r < 4; ++r) {
            float v = acc2[n][r] + bg[o];
#pragma unroll
            for (int kc = 0; kc < 6; ++kc) v += sSx[(il0 + r) * 6 + kc] * Wxg[kc * 128 + o];
            sg[r] = 1.f / (1.f + __expf(-v));
          }
          if (oh == 0) {
#pragma unroll
            for (int r = 0; r < 4; ++r) sZ[(il0 + r) * 64 + o] = sg[r];
          } else {
            int col = bcol + (o - 64);
            size_t cb = (size_t)col * 512 + i0 + (((il0 >> 3) ^ (col & 7)) << 3) + (il0 & 7);
            u16x4 h4 = *(const u16x4*)(Hhi + cb);   // own-block data
            u16x4 l4 = *(const u16x4*)(Hlo + cb);
            u16x4 oh4;
#pragma unroll
            for (int r = 0; r < 4; ++r) {
              float h = bf2f(h4[r]) + bf2f(l4[r]);
              oh4[r] = f2bf(sg[r] * h);
            }
            *(u16x4*)(RHhi + cb) = oh4;   // plain store (published by groupbar)
          }
        }
      } else {
        f32x4 acc2[2];
#pragma unroll
        for (int n = 0; n < 2; ++n) acc2[n] = (f32x4)(0.f);
#pragma unroll
        for (int s = 0; s < 3; ++s) {
          const unsigned short* Wsrc = (s < 2) ? Whuh : Whul;
          int abase = (s == 1) ? 200 : 0;
#pragma unroll
          for (int f = 0; f < 6; ++f) {
            int k0 = f * 32 + (L >> 4) * 8;
            v8s af2 = *(const v8s*)(sS + (me * 16 + (L & 15)) * 408 + abase + k0);
#pragma unroll
            for (int n = 0; n < 2; ++n) {
              v8s bf2 = *(const v8s*)(Wsrc + (size_t)(oh * 32 + n * 16 + (L & 15)) * 200 + k0);
              acc2[n] = __builtin_amdgcn_mfma_f32_16x16x32_bf16(af2, bf2, acc2[n], 0, 0, 0);
            }
          }
        }
#pragma unroll
        for (int n = 0; n < 2; ++n) {
          int o = oh * 32 + n * 16 + (L & 15);
          int il0 = me * 16 + (L >> 4) * 4;
          int col = bcol + o;
          size_t cb = (size_t)col * 512 + i0 + (((il0 >> 3) ^ (col & 7)) << 3) + (il0 & 7);
          u16x4 h4 = *(const u16x4*)(Hhi + cb);   // own-block data
          u16x4 l4 = *(const u16x4*)(Hlo + cb);
          u16x4 oh4, ol4;
#pragma unroll
          for (int r = 0; r < 4; ++r) {
            float v = acc2[n][r] + bu[o];
#pragma unroll
            for (int kc = 0; kc < 6; ++kc) v += sSx[(il0 + r) * 6 + kc] * Wxu[kc * 64 + o];
            float hc2 = fast_tanh(v);
            float z = sZ[(il0 + r) * 64 + o];
            float h = bf2f(h4[r]) + bf2f(l4[r]);
            float hn = (1.f - z) * h + z * hc2;
            unsigned short hi = f2bf(hn);
            oh4[r] = hi;
            ol4[r] = f2bf(hn - bf2f(hi));
            if (t == TT - 1) out[((size_t)b * 512 + i0 + il0 + r) * 64 + o] = hn;
          }
          *(u16x4*)(Hhi + cb) = oh4;
          *(u16x4*)(Hlo + cb) = ol4;
        }
      }
      // publish this phase's state writes; acquire peers' (skip after last phase)
      if (t != TT - 1 || ph != 1) groupbar(gb);
    }
  }
}

extern "C" void kernel_launch(void* const* d_in, const int* in_sizes, int n_in,
                              void* d_out, int out_size, void* d_ws, size_t ws_size,
                              hipStream_t stream) {
  const float* G      = (const float*)d_in[0];
  const float* x_seq  = (const float*)d_in[1];
  const float* init_h = (const float*)d_in[2];
  const float* Wg     = (const float*)d_in[3];
  const float* bg     = (const float*)d_in[4];
  const float* Wu     = (const float*)d_in[5];
  const float* bu     = (const float*)d_in[6];
  float* out = (float*)d_out;
  float* ws = (float*)d_ws;

  unsigned short* GHI  = (unsigned short*)(ws + OFF_GHI);
  unsigned short* GPK  = (unsigned short*)(ws + OFF_GPK);
  unsigned short* Xh   = (unsigned short*)(ws + OFF_XTH);
  float* Sx2           = ws + OFF_SX;
  unsigned short* Hhi  = (unsigned short*)(ws + OFF_HHI);
  unsigned short* Hlo  = (unsigned short*)(ws + OFF_HLO);
  unsigned short* RHhi = (unsigned short*)(ws + OFF_RHHI);
  unsigned int* bar    = (unsigned int*)(ws + OFF_BAR);
  unsigned short* Whgh = (unsigned short*)(ws + OFF_WHGH);
  unsigned short* Whgl = (unsigned short*)(ws + OFF_WHGL);
  unsigned short* Whuh = (unsigned short*)(ws + OFF_WHUH);
  unsigned short* Whul = (unsigned short*)(ws + OFF_WHUL);
  float* Wxg           = ws + OFF_WXG;
  float* Wxu           = ws + OFF_WXU;

  // Prologue: zero claim[8]+gbar[32][2]; one merged pack kernel; one Sx GEMM
  (void)hipMemsetAsync(bar, 0, (8 + 64) * 4, stream);
  prep_all<<<9237, 256, 0, stream>>>(G, x_seq, init_h, Wg, Wu, GHI, GPK, Xh,
                                     Hhi, Hlo, Whgh, Whgl, Whuh, Whul, Wxg, Wxu);
  gemm_sx<<<dim3(12, 24), 256, 0, stream>>>(GHI, Xh, Sx2);

  // Whole recurrence: one persistent kernel, per-b-group fenced barriers.
  persist<<<256, 512, 0, stream>>>(GPK, Hhi, Hlo, RHhi, Sx2,
                                   Whgh, Whgl, Wxg, bg, Whuh, Whul, Wxu, bu, out, bar);
}

// Round 20
// 357.943 us; speedup vs baseline: 3.5295x; 3.5295x over previous
//
#include <hip/hip_runtime.h>
#include <hip/hip_bf16.h>
#include <cmath>

// Problem constants
#define NN 512   // nodes
#define BB 32    // batch
#define HH 64    // hidden
#define TT 12    // timesteps
#define KS 3     // graph supports

// Workspace layout (float units)
#define OFF_GHI   0         // bf16 [1536][512] rows k*512+i, swizzled in j (gemm_sx)
#define OFF_GPK   786432    // bf16 fragment-major G (HI ONLY): 1536 frags x 512 shorts
#define OFF_XTH   1572864   // bf16 [768][512]
#define OFF_XTL   1769472
#define OFF_SX    1966080   // f32  [1536][768]
#define OFF_HHI   3145728   // bf16 [2048][512] col = b*64+q, swizzled in j(=i)
#define OFF_HLO   3670016
#define OFF_RHHI  4194304
#define OFF_Z     4718592   // f32 [32][512][64]
#define OFF_WHGH  6291456   // bf16 [128][200]
#define OFF_WHGL  6304256
#define OFF_WHUH  6317056   // bf16 [64][200]
#define OFF_WHUL  6323456
#define OFF_WXG   6329856   // f32 [6][128]
#define OFF_WXU   6330624   // f32 [6][64]

typedef __attribute__((ext_vector_type(8))) short v8s;
typedef __attribute__((ext_vector_type(4))) float f32x4;
typedef __attribute__((ext_vector_type(4))) unsigned short u16x4;

__device__ __forceinline__ unsigned short f2bf(float f) {
  union { __hip_bfloat16 h; unsigned short u; } x;
  x.h = __float2bfloat16(f);
  return x.u;
}
__device__ __forceinline__ float bf2f(unsigned short u) {
  union { unsigned short u; __hip_bfloat16 h; } x;
  x.u = u;
  return __bfloat162float(x.h);
}

__device__ __forceinline__ int swz64(int j, int key) {
  return (j & ~63) | ((((j >> 3) & 7) ^ key) << 3) | (j & 7);
}

__device__ __forceinline__ void gl_lds16(const unsigned short* g, short* l) {
  __builtin_amdgcn_global_load_lds(
      (const __attribute__((address_space(1))) void*)g,
      (__attribute__((address_space(3))) void*)l, 16, 0, 0);
}

__device__ __forceinline__ float fast_tanh(float x) {
  float e = __expf(2.f * x);
  return 1.f - 2.f / (e + 1.f);
}

// ---------------- merged prologue pack kernel ----------------
__global__ __launch_bounds__(256) void prep_all(
    const float* __restrict__ G, const float* __restrict__ x_seq,
    const float* __restrict__ init_h, const float* __restrict__ Wg,
    const float* __restrict__ Wu,
    unsigned short* __restrict__ Ghi, unsigned short* __restrict__ Gpk,
    unsigned short* __restrict__ Xh, unsigned short* __restrict__ Xl,
    unsigned short* __restrict__ Hhi, unsigned short* __restrict__ Hlo,
    unsigned short* __restrict__ Whgh, unsigned short* __restrict__ Whgl,
    unsigned short* __restrict__ Whuh, unsigned short* __restrict__ Whul,
    float* __restrict__ Wxg, float* __restrict__ Wxu) {
  int idx = blockIdx.x * 256 + threadIdx.x;
  if (idx < 786432) {
    int j = idx & 511;
    int i = (idx >> 9) & 511;
    Ghi[(size_t)(idx >> 9) * 512 + swz64(j, i & 7)] = f2bf(G[idx]);
  } else if (idx < 884736) {
    int t = idx - 786432;
    int L = t & 63;
    int frag = t >> 6;
    int m = frag % 3;
    int kf = (frag / 3) & 1;
    int j0 = (frag / 6) & 7;
    int i0w = frag / 48;
    int w = i0w & 3, i0 = i0w >> 2;
    int R = w * 48 + m * 16 + (L & 15);
    int ksec = R >> 6;
    int i = i0 * 64 + (R & 63);
    int jb = j0 * 64 + kf * 32 + (L >> 4) * 8;
    unsigned short* dst = Gpk + (size_t)frag * 512 + L * 8;
#pragma unroll
    for (int e = 0; e < 8; ++e) dst[e] = f2bf(G[((size_t)ksec * NN + i) * NN + jb + e]);
  } else if (idx < 1277952) {
    int t2 = idx - 884736;
    int j = t2 & 511;
    int col = t2 >> 9;          // t*64 + b*2 + c
    int t = col >> 6;
    int b = (col & 63) >> 1;
    int c = col & 1;
    float v = x_seq[((size_t)(b * TT + t) * NN + j) * 2 + c];
    unsigned short hi = f2bf(v);
    size_t pos = (size_t)col * 512 + swz64(j, col & 7);
    Xh[pos] = hi;
    Xl[pos] = f2bf(v - bf2f(hi));
  } else if (idx < 2326528) {
    int t2 = idx - 1277952;
    int i = t2 & 511;
    int col = t2 >> 9;
    int b = col >> 6;
    int p = col & 63;
    float h = init_h[((size_t)b * NN + i) * HH + p];
    unsigned short hi = f2bf(h);
    size_t pos = (size_t)col * 512 + swz64(i, col & 7);
    Hhi[pos] = hi;
    Hlo[pos] = f2bf(h - bf2f(hi));
  } else if (idx < 2364544) {
    int j2 = idx - 2326528;
    if (j2 < 24576) {
      int o = j2 & 127, kq = j2 >> 7;
      int k = kq >> 6, q = kq & 63;
      float v = Wg[(size_t)(k * 66 + 2 + q) * 128 + o];
      unsigned short hi = f2bf(v);
      Whgh[o * 200 + kq] = hi;
      Whgl[o * 200 + kq] = f2bf(v - bf2f(hi));
    } else if (j2 < 36864) {
      int j = j2 - 24576;
      int o = j & 63, kq = j >> 6;
      int k = kq >> 6, q = kq & 63;
      float v = Wu[(size_t)(k * 66 + 2 + q) * 64 + o];
      unsigned short hi = f2bf(v);
      Whuh[o * 200 + kq] = hi;
      Whul[o * 200 + kq] = f2bf(v - bf2f(hi));
    } else if (j2 < 37632) {
      int j = j2 - 36864;
      int o = j & 127, kc = j >> 7;
      Wxg[kc * 128 + o] = Wg[(size_t)((kc >> 1) * 66 + (kc & 1)) * 128 + o];
    } else {
      int j = j2 - 37632;
      int o = j & 63, kc = j >> 6;
      Wxu[kc * 64 + o] = Wu[(size_t)((kc >> 1) * 66 + (kc & 1)) * 64 + o];
    }
  }
}

// ---------------- Sx precompute: Ghi @ [Xhi ; Xlo], K = 1024 ----------------
__global__ __launch_bounds__(256) void gemm_sx(const unsigned short* __restrict__ Ghi,
                                               const unsigned short* __restrict__ Xh,
                                               const unsigned short* __restrict__ Xl,
                                               float* __restrict__ Sx2) {
  __shared__ __align__(16) short sA[64 * 64];
  __shared__ __align__(16) short sB[64 * 64];
  int tid = threadIdx.x;
  int L = tid & 63, w = tid >> 6;
  int wm = (w >> 1) * 32, wn = (w & 1) * 32;
  int i0 = blockIdx.y * 64;
  int c0 = blockIdx.x * 64;
  f32x4 acc[2][2];
#pragma unroll
  for (int m = 0; m < 2; ++m)
#pragma unroll
    for (int n = 0; n < 2; ++n) acc[m][n] = (f32x4)(0.f);

  for (int j0 = 0; j0 < 1024; j0 += 64) {
    const unsigned short* Bsel = (j0 < 512) ? Xh : Xl;
    int jb = j0 & 511;
    __syncthreads();
#pragma unroll
    for (int u = 0; u < 2; ++u) {
      int r = w * 16 + u * 8;
      gl_lds16(Ghi + (size_t)(i0 + r + (L >> 3)) * 512 + jb + (L & 7) * 8, sA + r * 64);
      gl_lds16(Bsel + (size_t)(c0 + r + (L >> 3)) * 512 + jb + (L & 7) * 8, sB + r * 64);
    }
    __syncthreads();
#pragma unroll
    for (int kf = 0; kf < 2; ++kf) {
      int kog = kf * 4 + (L >> 4);
      v8s af[2], bf[2];
#pragma unroll
      for (int m = 0; m < 2; ++m) {
        int row = wm + m * 16 + (L & 15);
        af[m] = *(const v8s*)(sA + row * 64 + ((kog ^ (row & 7)) << 3));
      }
#pragma unroll
      for (int n = 0; n < 2; ++n) {
        int row = wn + n * 16 + (L & 15);
        bf[n] = *(const v8s*)(sB + row * 64 + ((kog ^ (row & 7)) << 3));
      }
#pragma unroll
      for (int m = 0; m < 2; ++m)
#pragma unroll
        for (int n = 0; n < 2; ++n)
          acc[m][n] = __builtin_amdgcn_mfma_f32_16x16x32_bf16(af[m], bf[n], acc[m][n], 0, 0, 0);
    }
  }
#pragma unroll
  for (int m = 0; m < 2; ++m)
#pragma unroll
    for (int r = 0; r < 4; ++r)
#pragma unroll
      for (int n = 0; n < 2; ++n)
        Sx2[(size_t)(i0 + wm + m * 16 + (L >> 4) * 4 + r) * 768 + c0 + wn + n * 16 + (L & 15)] =
            acc[m][n][r];
}

// ---------------- fused half-step ----------------
// 256 blocks x 512 thr. Grid mapping gives each b-group (8 i-tiles of one b)
// the SAME bid&7 class -> same XCD under round-robin dispatch: the 64KB B slab
// is fetched once per XCD, and gate->update RH handoff stays XCD-local.
template <int GATE>
__global__ __launch_bounds__(512, 2) void fused_step(
    const unsigned short* __restrict__ Gpk,
    const unsigned short* __restrict__ Bhi,   // gate: Hhi ; upd: RHhi
    const float* __restrict__ Sx2,
    const unsigned short* __restrict__ Whi,   // [O][200]
    const unsigned short* __restrict__ Wlo,
    const float* __restrict__ Wx,             // [6][O]
    const float* __restrict__ bias,           // [O]
    const unsigned short* __restrict__ Hr_hi,
    const unsigned short* __restrict__ Hr_lo,
    unsigned short* __restrict__ Ohi,         // gate: RHhi ; upd: Hhi
    unsigned short* __restrict__ Olo,         // upd: Hlo (gate: unused)
    float* __restrict__ Z,
    float* __restrict__ out, int t) {
  constexpr int O = GATE ? 128 : 64;
  constexpr int NF = GATE ? 4 : 2;   // epilogue frags per wave (col-half O/2)
  __shared__ __align__(16) char smem[67584];
  short* sBh = (short*)smem;               // [64][512] (64 KB)
  short* sS  = (short*)smem;               // overlay after GEMM: [64][408]
  float* sSx = (float*)(smem + 65536);     // [64][6]

  int tid = threadIdx.x;
  int L = tid & 63, w = tid >> 6;
  int wm = w & 3, wn = w >> 2;
  int bid = blockIdx.x;
  int xcd = bid & 7, local = bid >> 3;
  int b = xcd * 4 + (local >> 3);    // 4 b per XCD class
  int i0t = local & 7;               // all 8 i-tiles of b share bid&7
  int i0 = i0t * 64;
  int bcol = b * 64;
  const unsigned short* Ap = Gpk + (size_t)(i0t * 4 + wm) * 48 * 512;

  // ---- stage B (hi only) + Sx ----
#pragma unroll
  for (int u = 0; u < 8; ++u) {
    int col = w * 8 + u;
    gl_lds16(Bhi + (size_t)(bcol + col) * 512 + L * 8, sBh + col * 512);
  }
  for (int e = tid; e < 384; e += 512) {
    int il = e / 6, kc = e % 6;
    sSx[e] = Sx2[(size_t)((kc >> 1) * 512 + i0 + il) * 768 + t * 64 + b * 2 + (kc & 1)];
  }
  __syncthreads();  // drains gl_lds: B + Sx staged

  // ---- main GEMM: S = Ghi @ Bhi (r13 loop form) ----
  f32x4 acc[3][2];
#pragma unroll
  for (int m = 0; m < 3; ++m)
#pragma unroll
    for (int n = 0; n < 2; ++n) acc[m][n] = (f32x4)(0.f);
#pragma unroll
  for (int it = 0; it < 8; ++it) {
    v8s ah[2][3];
#pragma unroll
    for (int kf = 0; kf < 2; ++kf)
#pragma unroll
      for (int m = 0; m < 3; ++m)
        ah[kf][m] = *(const v8s*)(Ap + (size_t)((it * 2 + kf) * 3 + m) * 512 + L * 8);
#pragma unroll
    for (int kf = 0; kf < 2; ++kf) {
      int jj = it * 64 + kf * 32 + (L >> 4) * 8;
      v8s bh[2];
#pragma unroll
      for (int n = 0; n < 2; ++n) {
        int col = wn * 32 + n * 16 + (L & 15);
        int off = col * 512 + ((jj & ~63) | (((((jj >> 3) & 7) ^ (col & 7))) << 3));
        bh[n] = *(const v8s*)(sBh + off);
      }
#pragma unroll
      for (int m = 0; m < 3; ++m)
#pragma unroll
        for (int n = 0; n < 2; ++n)
          acc[m][n] = __builtin_amdgcn_mfma_f32_16x16x32_bf16(ah[kf][m], bh[n], acc[m][n], 0, 0, 0);
    }
  }
  __syncthreads();  // all sBh reads done; sS overlay may overwrite

  // ---- write S to LDS as bf16 hi/lo ----
#pragma unroll
  for (int m = 0; m < 3; ++m)
#pragma unroll
    for (int n = 0; n < 2; ++n)
#pragma unroll
      for (int r = 0; r < 4; ++r) {
        int R = wm * 48 + m * 16 + (L >> 4) * 4 + r;
        int il = R & 63, kk = R >> 6;
        int p = wn * 32 + n * 16 + (L & 15);
        float v = acc[m][n][r];
        unsigned short hi = f2bf(v);
        sS[il * 408 + kk * 64 + p] = (short)hi;
        sS[il * 408 + 200 + kk * 64 + p] = (short)f2bf(v - bf2f(hi));
      }
  __syncthreads();

  // ---- epilogue: 8 waves, me = row-group, oh = col-half ----
  int me = w & 3, oh = w >> 2;
  f32x4 acc2[NF];
#pragma unroll
  for (int n = 0; n < NF; ++n) acc2[n] = (f32x4)(0.f);
#pragma unroll
  for (int s = 0; s < 3; ++s) {
    const unsigned short* Wsrc = (s < 2) ? Whi : Wlo;
    int abase = (s == 1) ? 200 : 0;
#pragma unroll
    for (int f = 0; f < 6; ++f) {
      int k0 = f * 32 + (L >> 4) * 8;
      v8s af2 = *(const v8s*)(sS + (me * 16 + (L & 15)) * 408 + abase + k0);
#pragma unroll
      for (int n = 0; n < NF; ++n) {
        v8s bf2 = *(const v8s*)(Wsrc + (size_t)(oh * (O / 2) + n * 16 + (L & 15)) * 200 + k0);
        acc2[n] = __builtin_amdgcn_mfma_f32_16x16x32_bf16(af2, bf2, acc2[n], 0, 0, 0);
      }
    }
  }

  // ---- x-part + bias + activation + state update ----
#pragma unroll
  for (int n = 0; n < NF; ++n) {
    int o = oh * (O / 2) + n * 16 + (L & 15);
    int il0 = me * 16 + (L >> 4) * 4;
    float vals[4];
#pragma unroll
    for (int r = 0; r < 4; ++r) {
      float v = acc2[n][r] + bias[o];
#pragma unroll
      for (int kc = 0; kc < 6; ++kc) v += sSx[(il0 + r) * 6 + kc] * Wx[kc * O + o];
      vals[r] = v;
    }
    if (GATE) {
      float sg[4];
#pragma unroll
      for (int r = 0; r < 4; ++r) sg[r] = 1.f / (1.f + __expf(-vals[r]));
      if (oh == 0) {  // o in 0..63 -> z
#pragma unroll
        for (int r = 0; r < 4; ++r)
          Z[((size_t)b * 512 + i0 + il0 + r) * 64 + o] = sg[r];
      } else {        // o in 64..127 -> r-gate
        int col = bcol + (o - 64);
        size_t cb = (size_t)col * 512 + i0 + (((il0 >> 3) ^ (col & 7)) << 3) + (il0 & 7);
        u16x4 h4 = *(const u16x4*)(Hr_hi + cb);
        u16x4 l4 = *(const u16x4*)(Hr_lo + cb);
        u16x4 oh4;
#pragma unroll
        for (int r = 0; r < 4; ++r) {
          float h = bf2f(h4[r]) + bf2f(l4[r]);
          oh4[r] = f2bf(sg[r] * h);
        }
        *(u16x4*)(Ohi + cb) = oh4;   // RH hi only
      }
    } else {
      int col = bcol + o;
      size_t cb = (size_t)col * 512 + i0 + (((il0 >> 3) ^ (col & 7)) << 3) + (il0 & 7);
      u16x4 h4 = *(const u16x4*)(Hr_hi + cb);
      u16x4 l4 = *(const u16x4*)(Hr_lo + cb);
      u16x4 oh4, ol4;
#pragma unroll
      for (int r = 0; r < 4; ++r) {
        float hc = fast_tanh(vals[r]);
        float z = Z[((size_t)b * 512 + i0 + il0 + r) * 64 + o];
        float h = bf2f(h4[r]) + bf2f(l4[r]);
        float hn = (1.f - z) * h + z * hc;
        unsigned short hi = f2bf(hn);
        oh4[r] = hi;
        ol4[r] = f2bf(hn - bf2f(hi));   // h carried hi+lo
        if (t == TT - 1) out[((size_t)b * 512 + i0 + il0 + r) * 64 + o] = hn;
      }
      *(u16x4*)(Ohi + cb) = oh4;
      *(u16x4*)(Olo + cb) = ol4;
    }
  }
}

extern "C" void kernel_launch(void* const* d_in, const int* in_sizes, int n_in,
                              void* d_out, int out_size, void* d_ws, size_t ws_size,
                              hipStream_t stream) {
  const float* G      = (const float*)d_in[0];
  const float* x_seq  = (const float*)d_in[1];
  const float* init_h = (const float*)d_in[2];
  const float* Wg     = (const float*)d_in[3];
  const float* bg     = (const float*)d_in[4];
  const float* Wu     = (const float*)d_in[5];
  const float* bu     = (const float*)d_in[6];
  float* out = (float*)d_out;
  float* ws = (float*)d_ws;

  unsigned short* GHI  = (unsigned short*)(ws + OFF_GHI);
  unsigned short* GPK  = (unsigned short*)(ws + OFF_GPK);
  unsigned short* Xh   = (unsigned short*)(ws + OFF_XTH);
  unsigned short* Xl   = (unsigned short*)(ws + OFF_XTL);
  float* Sx2           = ws + OFF_SX;
  unsigned short* Hhi  = (unsigned short*)(ws + OFF_HHI);
  unsigned short* Hlo  = (unsigned short*)(ws + OFF_HLO);
  unsigned short* RHhi = (unsigned short*)(ws + OFF_RHHI);
  float* Z             = ws + OFF_Z;
  unsigned short* Whgh = (unsigned short*)(ws + OFF_WHGH);
  unsigned short* Whgl = (unsigned short*)(ws + OFF_WHGL);
  unsigned short* Whuh = (unsigned short*)(ws + OFF_WHUH);
  unsigned short* Whul = (unsigned short*)(ws + OFF_WHUL);
  float* Wxg           = ws + OFF_WXG;
  float* Wxu           = ws + OFF_WXU;

  // Prologue: one merged pack kernel + one Sx GEMM
  prep_all<<<9237, 256, 0, stream>>>(G, x_seq, init_h, Wg, Wu, GHI, GPK, Xh, Xl,
                                     Hhi, Hlo, Whgh, Whgl, Whuh, Whul, Wxg, Wxu);
  gemm_sx<<<dim3(12, 24), 256, 0, stream>>>(GHI, Xh, Xl, Sx2);

  for (int t = 0; t < TT; ++t) {
    fused_step<1><<<256, 512, 0, stream>>>(GPK, Hhi, Sx2, Whgh, Whgl, Wxg, bg,
                                           Hhi, Hlo, RHhi, RHhi, Z, out, t);
    fused_step<0><<<256, 512, 0, stream>>>(GPK, RHhi, Sx2, Whuh, Whul, Wxu, bu,
                                           Hhi, Hlo, Hhi, Hlo, Z, out, t);
  }
}